// Round 6
// baseline (154.725 us; speedup 1.0000x reference)
//
#include <hip/hip_runtime.h>
#include <cstddef>

#define BS_   4
#define CH_   3
#define HH    512
#define WW    512
#define KS    11
#define K2_   (KS*KS)          // 121
#define HW_   (HH*WW)          // 262144
#define PADL  5
#define PADR  11
#define PW_   (PADL + WW + PADR)  // 528 -> row stride 2112 B, 16B-aligned
#define PX    4                // pixels per thread in x

typedef float f4 __attribute__((ext_vector_type(4)));

// ---------------------------------------------------------------------------
// Pad data in x into d_ws: [BS][CH][H][PW_], zero outside [PADL, PADL+W).
// Rewritten fully every call (d_ws is poisoned once, never re-poisoned).
// ---------------------------------------------------------------------------
__global__ void pad_data_kernel(const float* __restrict__ data,
                                float* __restrict__ dpad) {
  int idx = blockIdx.x * 256 + threadIdx.x;
  const int total = BS_ * CH_ * HH * PW_;
  if (idx >= total) return;
  int col  = idx % PW_;
  int rest = idx / PW_;            // (b*CH + c)*H + row
  int sc   = col - PADL;
  float v = 0.0f;
  if (sc >= 0 && sc < WW) v = data[(size_t)rest * WW + sc];
  dpad[idx] = v;
}

// ---------------------------------------------------------------------------
// Fused ProgressiveKernelApply update. One thread = 4 consecutive x-pixels.
// Single pass over the 121 kernel taps using exp(k-nm) = exp(k)*exp(-nm).
// A/B vs R5: kernels loads are PLAIN (nontemporal removed) — probing whether
// nt/sc1 reads fetch at reduced granularity and halve stream BW. Everything
// else identical to R5 (145.7 us).
// ---------------------------------------------------------------------------
template<bool PADDED>
__global__ __launch_bounds__(128, 4)
void pka_kernel(const float* __restrict__ kern,
                const float* __restrict__ data,
                const float* __restrict__ dpad,
                const float* __restrict__ sum_r_in,
                const float* __restrict__ sum_w_in,
                const float* __restrict__ max_w_in,
                float* __restrict__ out) {
  const int tx = threadIdx.x;                 // 0..63
  const int ty = threadIdx.y;                 // 0..1 (wave-uniform rows)
  const int X  = blockIdx.x * (64 * PX) + tx * PX;  // base output col
  const int y  = blockIdx.y * 2 + ty;
  const int b  = blockIdx.z;

  // x-validity mask per window index j (source col = X-5+j), j = dx + p
  float vld[14];
  int colc[14];
  #pragma unroll
  for (int j = 0; j < 14; ++j) {
    int col = X - PADL + j;
    vld[j] = (col >= 0 && col < WW) ? 1.0f : 0.0f;
    if constexpr (!PADDED) colc[j] = min(max(col, 0), WW - 1);
    else colc[j] = 0;
  }

  float m0 = -3.0e38f, m1 = -3.0e38f, m2 = -3.0e38f, m3 = -3.0e38f;
  float sw0 = 0.f, sw1 = 0.f, sw2 = 0.f, sw3 = 0.f;
  float sr[CH_][PX];
  #pragma unroll
  for (int c = 0; c < CH_; ++c)
    #pragma unroll
    for (int p = 0; p < PX; ++p) sr[c][p] = 0.f;

  const float* kb = kern + (((size_t)b * K2_) * HH + y) * WW + X;

  #pragma unroll 1
  for (int dy = 0; dy < KS; ++dy) {
    // --- load 11 x 16B kernel taps for this dy (coalesced, PLAIN loads) ---
    f4 kv[KS];
    #pragma unroll
    for (int dx = 0; dx < KS; ++dx)
      kv[dx] = *reinterpret_cast<const f4*>(kb + (size_t)(dy * KS + dx) * HW_);

    // --- running max over ALL taps (reference kmax is unconditional) ---
    #pragma unroll
    for (int dx = 0; dx < KS; ++dx) {
      m0 = fmaxf(m0, kv[dx].x);
      m1 = fmaxf(m1, kv[dx].y);
      m2 = fmaxf(m2, kv[dx].z);
      m3 = fmaxf(m3, kv[dx].w);
    }

    const int sy = y + dy - PADL;
    if (sy >= 0 && sy < HH) {        // wave-uniform (ty uniform per wave)
      // exp in place
      #pragma unroll
      for (int dx = 0; dx < KS; ++dx) {
        kv[dx].x = __expf(kv[dx].x);
        kv[dx].y = __expf(kv[dx].y);
        kv[dx].z = __expf(kv[dx].z);
        kv[dx].w = __expf(kv[dx].w);
      }
      // sum_w: validity-masked accumulate
      #pragma unroll
      for (int dx = 0; dx < KS; ++dx) {
        sw0 += kv[dx].x * vld[dx + 0];
        sw1 += kv[dx].y * vld[dx + 1];
        sw2 += kv[dx].z * vld[dx + 2];
        sw3 += kv[dx].w * vld[dx + 3];
      }
      // sum_r per channel (d[16] is transient; reused across channels)
      #pragma unroll
      for (int c = 0; c < CH_; ++c) {
        float d[16];
        if constexpr (PADDED) {
          const float* rp = dpad + (((size_t)b * CH_ + c) * HH + sy) * PW_ + X;
          f4 a0 = *reinterpret_cast<const f4*>(rp);
          f4 a1 = *reinterpret_cast<const f4*>(rp + 4);
          f4 a2 = *reinterpret_cast<const f4*>(rp + 8);
          f4 a3 = *reinterpret_cast<const f4*>(rp + 12);
          d[0]=a0.x; d[1]=a0.y; d[2]=a0.z;  d[3]=a0.w;
          d[4]=a1.x; d[5]=a1.y; d[6]=a1.z;  d[7]=a1.w;
          d[8]=a2.x; d[9]=a2.y; d[10]=a2.z; d[11]=a2.w;
          d[12]=a3.x; d[13]=a3.y; d[14]=a3.z; d[15]=a3.w;
        } else {
          const float* rp = data + (((size_t)b * CH_ + c) * HH + sy) * WW;
          #pragma unroll
          for (int j = 0; j < 14; ++j) d[j] = rp[colc[j]] * vld[j];
          d[14] = 0.f; d[15] = 0.f;
        }
        #pragma unroll
        for (int dx = 0; dx < KS; ++dx) {
          sr[c][0] += kv[dx].x * d[dx + 0];
          sr[c][1] += kv[dx].y * d[dx + 1];
          sr[c][2] += kv[dx].z * d[dx + 2];
          sr[c][3] += kv[dx].w * d[dx + 3];
        }
      }
    }
  }

  // ------------------------------- epilogue -------------------------------
  const size_t pix = ((size_t)b * HH + y) * WW + X;
  f4 mw  = *reinterpret_cast<const f4*>(max_w_in + pix);
  f4 swi = *reinterpret_cast<const f4*>(sum_w_in + pix);

  float nm0 = fmaxf(m0, mw.x), nm1 = fmaxf(m1, mw.y);
  float nm2 = fmaxf(m2, mw.z), nm3 = fmaxf(m3, mw.w);
  float sc0 = __expf(mw.x - nm0), sc1 = __expf(mw.y - nm1);
  float sc2 = __expf(mw.z - nm2), sc3 = __expf(mw.w - nm3);
  float iv0 = __expf(-nm0), iv1 = __expf(-nm1);
  float iv2 = __expf(-nm2), iv3 = __expf(-nm3);

  // sum_r outputs (write-once -> nontemporal)
  #pragma unroll
  for (int c = 0; c < CH_; ++c) {
    const size_t off = (((size_t)b * CH_ + c) * HH + y) * WW + X;
    f4 sri = *reinterpret_cast<const f4*>(sum_r_in + off);
    f4 o;
    o.x = sri.x * sc0 + sr[c][0] * iv0;
    o.y = sri.y * sc1 + sr[c][1] * iv1;
    o.z = sri.z * sc2 + sr[c][2] * iv2;
    o.w = sri.w * sc3 + sr[c][3] * iv3;
    __builtin_nontemporal_store(o, reinterpret_cast<f4*>(out + off));
  }
  // sum_w output
  {
    f4 o;
    o.x = swi.x * sc0 + sw0 * iv0;
    o.y = swi.y * sc1 + sw1 * iv1;
    o.z = swi.z * sc2 + sw2 * iv2;
    o.w = swi.w * sc3 + sw3 * iv3;
    __builtin_nontemporal_store(
        o, reinterpret_cast<f4*>(out + (size_t)BS_ * CH_ * HW_ + pix));
  }
  // new_max output
  {
    f4 o; o.x = nm0; o.y = nm1; o.z = nm2; o.w = nm3;
    __builtin_nontemporal_store(
        o, reinterpret_cast<f4*>(out + (size_t)BS_ * CH_ * HW_ +
                                 (size_t)BS_ * HW_ + pix));
  }
}

// ---------------------------------------------------------------------------
extern "C" void kernel_launch(void* const* d_in, const int* in_sizes, int n_in,
                              void* d_out, int out_size, void* d_ws, size_t ws_size,
                              hipStream_t stream) {
  const float* data  = (const float*)d_in[0];
  const float* kern  = (const float*)d_in[1];
  const float* sum_r = (const float*)d_in[2];
  const float* sum_w = (const float*)d_in[3];
  const float* max_w = (const float*)d_in[4];
  float* out = (float*)d_out;

  dim3 block(64, 2, 1);
  dim3 grid(WW / (64 * PX), HH / 2, BS_);   // 2 x 256 x 4 = 2048 blocks

  const size_t padded_bytes = (size_t)BS_ * CH_ * HH * PW_ * sizeof(float);
  if (ws_size >= padded_bytes) {
    float* dpad = (float*)d_ws;
    const int total = BS_ * CH_ * HH * PW_;
    pad_data_kernel<<<(total + 255) / 256, 256, 0, stream>>>(data, dpad);
    pka_kernel<true><<<grid, block, 0, stream>>>(kern, data, dpad, sum_r,
                                                 sum_w, max_w, out);
  } else {
    pka_kernel<false><<<grid, block, 0, stream>>>(kern, data, nullptr, sum_r,
                                                  sum_w, max_w, out);
  }
}

// Round 7
// 147.346 us; speedup vs baseline: 1.0501x; 1.0501x over previous
//
#include <hip/hip_runtime.h>
#include <cstddef>

#define BS_   4
#define CH_   3
#define HH    512
#define WW    512
#define KS    11
#define K2_   (KS*KS)          // 121
#define HW_   (HH*WW)          // 262144
#define PADL  5
#define PADR  11
#define PW_   (PADL + WW + PADR)  // 528 -> row stride 2112 B, 16B-aligned
#define PX    4                // pixels per thread in x
#define NXCD  8

typedef float f4 __attribute__((ext_vector_type(4)));

// ---------------------------------------------------------------------------
// Pad data in x into d_ws: [BS][CH][H][PW_], zero outside [PADL, PADL+W).
// Rewritten fully every call (d_ws is poisoned once, never re-poisoned).
// ---------------------------------------------------------------------------
__global__ void pad_data_kernel(const float* __restrict__ data,
                                float* __restrict__ dpad) {
  int idx = blockIdx.x * 256 + threadIdx.x;
  const int total = BS_ * CH_ * HH * PW_;
  if (idx >= total) return;
  int col  = idx % PW_;
  int rest = idx / PW_;            // (b*CH + c)*H + row
  int sc   = col - PADL;
  float v = 0.0f;
  if (sc >= 0 && sc < WW) v = data[(size_t)rest * WW + sc];
  dpad[idx] = v;
}

// ---------------------------------------------------------------------------
// Fused ProgressiveKernelApply update. One thread = 4 consecutive x-pixels.
// Single pass over the 121 kernel taps using exp(k-nm) = exp(k)*exp(-nm).
// R7: NT loads restored (R6 A/B: removing them cost +9us) + XCD-aware block
// swizzle (T1): consecutive blockIdx round-robin XCDs, so y-adjacent blocks
// (sharing 10/11 dpad rows + adjacent kernels-plane rows) were split across
// L2s. newid=(l%8)*256+l/8 gives each XCD a contiguous 128-row y-band:
// dpad/XCD ~0.9MB (L2-resident), kernels stream y-contiguous per XCD.
// ---------------------------------------------------------------------------
template<bool PADDED>
__global__ __launch_bounds__(128, 4)
void pka_kernel(const float* __restrict__ kern,
                const float* __restrict__ data,
                const float* __restrict__ dpad,
                const float* __restrict__ sum_r_in,
                const float* __restrict__ sum_w_in,
                const float* __restrict__ max_w_in,
                float* __restrict__ out) {
  // ---- XCD swizzle: grid is 1-D (2048 blocks); decode (bx,by,bz) ----
  const int l     = blockIdx.x;                 // 0..2047
  const int newid = (l & (NXCD - 1)) * (2048 / NXCD) + (l >> 3);
  const int bx = newid & 1;                     // 0..1   (x half)
  const int by = (newid >> 1) & 255;            // 0..255 (y pair)
  const int bz = newid >> 9;                    // 0..3   (batch)

  const int tx = threadIdx.x;                   // 0..63
  const int ty = threadIdx.y;                   // 0..1 (wave-uniform rows)
  const int X  = bx * (64 * PX) + tx * PX;      // base output col
  const int y  = by * 2 + ty;
  const int b  = bz;

  // x-validity mask per window index j (source col = X-5+j), j = dx + p
  float vld[14];
  int colc[14];
  #pragma unroll
  for (int j = 0; j < 14; ++j) {
    int col = X - PADL + j;
    vld[j] = (col >= 0 && col < WW) ? 1.0f : 0.0f;
    if constexpr (!PADDED) colc[j] = min(max(col, 0), WW - 1);
    else colc[j] = 0;
  }

  float m0 = -3.0e38f, m1 = -3.0e38f, m2 = -3.0e38f, m3 = -3.0e38f;
  float sw0 = 0.f, sw1 = 0.f, sw2 = 0.f, sw3 = 0.f;
  float sr[CH_][PX];
  #pragma unroll
  for (int c = 0; c < CH_; ++c)
    #pragma unroll
    for (int p = 0; p < PX; ++p) sr[c][p] = 0.f;

  const float* kb = kern + (((size_t)b * K2_) * HH + y) * WW + X;

  #pragma unroll 1
  for (int dy = 0; dy < KS; ++dy) {
    // --- load 11 x 16B kernel taps for this dy (coalesced, nontemporal:
    //     507 MB read-once stream must not evict dpad from L2) ---
    f4 kv[KS];
    #pragma unroll
    for (int dx = 0; dx < KS; ++dx)
      kv[dx] = __builtin_nontemporal_load(
          reinterpret_cast<const f4*>(kb + (size_t)(dy * KS + dx) * HW_));

    // --- running max over ALL taps (reference kmax is unconditional) ---
    #pragma unroll
    for (int dx = 0; dx < KS; ++dx) {
      m0 = fmaxf(m0, kv[dx].x);
      m1 = fmaxf(m1, kv[dx].y);
      m2 = fmaxf(m2, kv[dx].z);
      m3 = fmaxf(m3, kv[dx].w);
    }

    const int sy = y + dy - PADL;
    if (sy >= 0 && sy < HH) {        // wave-uniform (ty uniform per wave)
      // exp in place
      #pragma unroll
      for (int dx = 0; dx < KS; ++dx) {
        kv[dx].x = __expf(kv[dx].x);
        kv[dx].y = __expf(kv[dx].y);
        kv[dx].z = __expf(kv[dx].z);
        kv[dx].w = __expf(kv[dx].w);
      }
      // sum_w: validity-masked accumulate
      #pragma unroll
      for (int dx = 0; dx < KS; ++dx) {
        sw0 += kv[dx].x * vld[dx + 0];
        sw1 += kv[dx].y * vld[dx + 1];
        sw2 += kv[dx].z * vld[dx + 2];
        sw3 += kv[dx].w * vld[dx + 3];
      }
      // sum_r per channel (d[16] is transient; reused across channels)
      #pragma unroll
      for (int c = 0; c < CH_; ++c) {
        float d[16];
        if constexpr (PADDED) {
          const float* rp = dpad + (((size_t)b * CH_ + c) * HH + sy) * PW_ + X;
          f4 a0 = *reinterpret_cast<const f4*>(rp);
          f4 a1 = *reinterpret_cast<const f4*>(rp + 4);
          f4 a2 = *reinterpret_cast<const f4*>(rp + 8);
          f4 a3 = *reinterpret_cast<const f4*>(rp + 12);
          d[0]=a0.x; d[1]=a0.y; d[2]=a0.z;  d[3]=a0.w;
          d[4]=a1.x; d[5]=a1.y; d[6]=a1.z;  d[7]=a1.w;
          d[8]=a2.x; d[9]=a2.y; d[10]=a2.z; d[11]=a2.w;
          d[12]=a3.x; d[13]=a3.y; d[14]=a3.z; d[15]=a3.w;
        } else {
          const float* rp = data + (((size_t)b * CH_ + c) * HH + sy) * WW;
          #pragma unroll
          for (int j = 0; j < 14; ++j) d[j] = rp[colc[j]] * vld[j];
          d[14] = 0.f; d[15] = 0.f;
        }
        #pragma unroll
        for (int dx = 0; dx < KS; ++dx) {
          sr[c][0] += kv[dx].x * d[dx + 0];
          sr[c][1] += kv[dx].y * d[dx + 1];
          sr[c][2] += kv[dx].z * d[dx + 2];
          sr[c][3] += kv[dx].w * d[dx + 3];
        }
      }
    }
  }

  // ------------------------------- epilogue -------------------------------
  const size_t pix = ((size_t)b * HH + y) * WW + X;
  f4 mw  = *reinterpret_cast<const f4*>(max_w_in + pix);
  f4 swi = *reinterpret_cast<const f4*>(sum_w_in + pix);

  float nm0 = fmaxf(m0, mw.x), nm1 = fmaxf(m1, mw.y);
  float nm2 = fmaxf(m2, mw.z), nm3 = fmaxf(m3, mw.w);
  float sc0 = __expf(mw.x - nm0), sc1 = __expf(mw.y - nm1);
  float sc2 = __expf(mw.z - nm2), sc3 = __expf(mw.w - nm3);
  float iv0 = __expf(-nm0), iv1 = __expf(-nm1);
  float iv2 = __expf(-nm2), iv3 = __expf(-nm3);

  // sum_r outputs (write-once -> nontemporal)
  #pragma unroll
  for (int c = 0; c < CH_; ++c) {
    const size_t off = (((size_t)b * CH_ + c) * HH + y) * WW + X;
    f4 sri = *reinterpret_cast<const f4*>(sum_r_in + off);
    f4 o;
    o.x = sri.x * sc0 + sr[c][0] * iv0;
    o.y = sri.y * sc1 + sr[c][1] * iv1;
    o.z = sri.z * sc2 + sr[c][2] * iv2;
    o.w = sri.w * sc3 + sr[c][3] * iv3;
    __builtin_nontemporal_store(o, reinterpret_cast<f4*>(out + off));
  }
  // sum_w output
  {
    f4 o;
    o.x = swi.x * sc0 + sw0 * iv0;
    o.y = swi.y * sc1 + sw1 * iv1;
    o.z = swi.z * sc2 + sw2 * iv2;
    o.w = swi.w * sc3 + sw3 * iv3;
    __builtin_nontemporal_store(
        o, reinterpret_cast<f4*>(out + (size_t)BS_ * CH_ * HW_ + pix));
  }
  // new_max output
  {
    f4 o; o.x = nm0; o.y = nm1; o.z = nm2; o.w = nm3;
    __builtin_nontemporal_store(
        o, reinterpret_cast<f4*>(out + (size_t)BS_ * CH_ * HW_ +
                                 (size_t)BS_ * HW_ + pix));
  }
}

// ---------------------------------------------------------------------------
extern "C" void kernel_launch(void* const* d_in, const int* in_sizes, int n_in,
                              void* d_out, int out_size, void* d_ws, size_t ws_size,
                              hipStream_t stream) {
  const float* data  = (const float*)d_in[0];
  const float* kern  = (const float*)d_in[1];
  const float* sum_r = (const float*)d_in[2];
  const float* sum_w = (const float*)d_in[3];
  const float* max_w = (const float*)d_in[4];
  float* out = (float*)d_out;

  dim3 block(64, 2, 1);
  dim3 grid(2048, 1, 1);   // 1-D; (bx,by,bz) decoded after XCD swizzle

  const size_t padded_bytes = (size_t)BS_ * CH_ * HH * PW_ * sizeof(float);
  if (ws_size >= padded_bytes) {
    float* dpad = (float*)d_ws;
    const int total = BS_ * CH_ * HH * PW_;
    pad_data_kernel<<<(total + 255) / 256, 256, 0, stream>>>(data, dpad);
    pka_kernel<true><<<grid, block, 0, stream>>>(kern, data, dpad, sum_r,
                                                 sum_w, max_w, out);
  } else {
    pka_kernel<false><<<grid, block, 0, stream>>>(kern, data, nullptr, sum_r,
                                                  sum_w, max_w, out);
  }
}

// Round 8
// 146.691 us; speedup vs baseline: 1.0548x; 1.0045x over previous
//
#include <hip/hip_runtime.h>
#include <cstddef>

#define BS_   4
#define CH_   3
#define HH    512
#define WW    512
#define KS    11
#define K2_   (KS*KS)          // 121
#define HW_   (HH*WW)          // 262144
#define PADL  5
#define PADR  11
#define PW_   (PADL + WW + PADR)  // 528 -> row stride 2112 B, 16B-aligned
#define PX    4                // pixels per thread in x

typedef float f4 __attribute__((ext_vector_type(4)));

// ---------------------------------------------------------------------------
// Pad data in x into d_ws: [BS][CH][H][PW_], zero outside [PADL, PADL+W).
// Rewritten fully every call (d_ws is poisoned once, never re-poisoned).
// ---------------------------------------------------------------------------
__global__ void pad_data_kernel(const float* __restrict__ data,
                                float* __restrict__ dpad) {
  int idx = blockIdx.x * 256 + threadIdx.x;
  const int total = BS_ * CH_ * HH * PW_;
  if (idx >= total) return;
  int col  = idx % PW_;
  int rest = idx / PW_;            // (b*CH + c)*H + row
  int sc   = col - PADL;
  float v = 0.0f;
  if (sc >= 0 && sc < WW) v = data[(size_t)rest * WW + sc];
  dpad[idx] = v;
}

// ---------------------------------------------------------------------------
// Fused ProgressiveKernelApply update. One thread = 4 consecutive x-pixels.
// Single pass over the 121 kernel taps using exp(k-nm) = exp(k)*exp(-nm).
//
// R8 geometry probe: block(128,1) -> the block's 2 waves cover the two
// adjacent 1KB halves of the SAME 2KB plane-row, __syncthreads()-paced per
// dy, so every in-flight HBM window is a full contiguous 2KB DRAM row
// (vs R5's scattered 1KB windows at ~60% read efficiency).
// NT loads kept (R6 A/B: +9us). XCD swizzle dropped (R7: null).
// ---------------------------------------------------------------------------
template<bool PADDED>
__global__ __launch_bounds__(128, 4)
void pka_kernel(const float* __restrict__ kern,
                const float* __restrict__ data,
                const float* __restrict__ dpad,
                const float* __restrict__ sum_r_in,
                const float* __restrict__ sum_w_in,
                const float* __restrict__ max_w_in,
                float* __restrict__ out) {
  const int tx = threadIdx.x;                   // 0..127 (2 waves, same row)
  const int X  = tx * PX;                       // 0..508: full 512-px row
  const int y  = blockIdx.y;
  const int b  = blockIdx.z;

  // x-validity mask per window index j (source col = X-5+j), j = dx + p
  float vld[14];
  int colc[14];
  #pragma unroll
  for (int j = 0; j < 14; ++j) {
    int col = X - PADL + j;
    vld[j] = (col >= 0 && col < WW) ? 1.0f : 0.0f;
    if constexpr (!PADDED) colc[j] = min(max(col, 0), WW - 1);
    else colc[j] = 0;
  }

  float m0 = -3.0e38f, m1 = -3.0e38f, m2 = -3.0e38f, m3 = -3.0e38f;
  float sw0 = 0.f, sw1 = 0.f, sw2 = 0.f, sw3 = 0.f;
  float sr[CH_][PX];
  #pragma unroll
  for (int c = 0; c < CH_; ++c)
    #pragma unroll
    for (int p = 0; p < PX; ++p) sr[c][p] = 0.f;

  const float* kb = kern + (((size_t)b * K2_) * HH + y) * WW + X;

  #pragma unroll 1
  for (int dy = 0; dy < KS; ++dy) {
    // keep the two row-half waves time-locked so their adjacent 1KB
    // requests form one contiguous 2KB DRAM-row read
    __syncthreads();

    // --- load 11 x 16B kernel taps for this dy (coalesced, nontemporal) ---
    f4 kv[KS];
    #pragma unroll
    for (int dx = 0; dx < KS; ++dx)
      kv[dx] = __builtin_nontemporal_load(
          reinterpret_cast<const f4*>(kb + (size_t)(dy * KS + dx) * HW_));

    // --- running max over ALL taps (reference kmax is unconditional) ---
    #pragma unroll
    for (int dx = 0; dx < KS; ++dx) {
      m0 = fmaxf(m0, kv[dx].x);
      m1 = fmaxf(m1, kv[dx].y);
      m2 = fmaxf(m2, kv[dx].z);
      m3 = fmaxf(m3, kv[dx].w);
    }

    const int sy = y + dy - PADL;
    if (sy >= 0 && sy < HH) {        // block-uniform branch
      // exp in place
      #pragma unroll
      for (int dx = 0; dx < KS; ++dx) {
        kv[dx].x = __expf(kv[dx].x);
        kv[dx].y = __expf(kv[dx].y);
        kv[dx].z = __expf(kv[dx].z);
        kv[dx].w = __expf(kv[dx].w);
      }
      // sum_w: validity-masked accumulate
      #pragma unroll
      for (int dx = 0; dx < KS; ++dx) {
        sw0 += kv[dx].x * vld[dx + 0];
        sw1 += kv[dx].y * vld[dx + 1];
        sw2 += kv[dx].z * vld[dx + 2];
        sw3 += kv[dx].w * vld[dx + 3];
      }
      // sum_r per channel (d[16] is transient; reused across channels)
      #pragma unroll
      for (int c = 0; c < CH_; ++c) {
        float d[16];
        if constexpr (PADDED) {
          const float* rp = dpad + (((size_t)b * CH_ + c) * HH + sy) * PW_ + X;
          f4 a0 = *reinterpret_cast<const f4*>(rp);
          f4 a1 = *reinterpret_cast<const f4*>(rp + 4);
          f4 a2 = *reinterpret_cast<const f4*>(rp + 8);
          f4 a3 = *reinterpret_cast<const f4*>(rp + 12);
          d[0]=a0.x; d[1]=a0.y; d[2]=a0.z;  d[3]=a0.w;
          d[4]=a1.x; d[5]=a1.y; d[6]=a1.z;  d[7]=a1.w;
          d[8]=a2.x; d[9]=a2.y; d[10]=a2.z; d[11]=a2.w;
          d[12]=a3.x; d[13]=a3.y; d[14]=a3.z; d[15]=a3.w;
        } else {
          const float* rp = data + (((size_t)b * CH_ + c) * HH + sy) * WW;
          #pragma unroll
          for (int j = 0; j < 14; ++j) d[j] = rp[colc[j]] * vld[j];
          d[14] = 0.f; d[15] = 0.f;
        }
        #pragma unroll
        for (int dx = 0; dx < KS; ++dx) {
          sr[c][0] += kv[dx].x * d[dx + 0];
          sr[c][1] += kv[dx].y * d[dx + 1];
          sr[c][2] += kv[dx].z * d[dx + 2];
          sr[c][3] += kv[dx].w * d[dx + 3];
        }
      }
    }
  }

  // ------------------------------- epilogue -------------------------------
  const size_t pix = ((size_t)b * HH + y) * WW + X;
  f4 mw  = *reinterpret_cast<const f4*>(max_w_in + pix);
  f4 swi = *reinterpret_cast<const f4*>(sum_w_in + pix);

  float nm0 = fmaxf(m0, mw.x), nm1 = fmaxf(m1, mw.y);
  float nm2 = fmaxf(m2, mw.z), nm3 = fmaxf(m3, mw.w);
  float sc0 = __expf(mw.x - nm0), sc1 = __expf(mw.y - nm1);
  float sc2 = __expf(mw.z - nm2), sc3 = __expf(mw.w - nm3);
  float iv0 = __expf(-nm0), iv1 = __expf(-nm1);
  float iv2 = __expf(-nm2), iv3 = __expf(-nm3);

  // sum_r outputs (write-once -> nontemporal)
  #pragma unroll
  for (int c = 0; c < CH_; ++c) {
    const size_t off = (((size_t)b * CH_ + c) * HH + y) * WW + X;
    f4 sri = *reinterpret_cast<const f4*>(sum_r_in + off);
    f4 o;
    o.x = sri.x * sc0 + sr[c][0] * iv0;
    o.y = sri.y * sc1 + sr[c][1] * iv1;
    o.z = sri.z * sc2 + sr[c][2] * iv2;
    o.w = sri.w * sc3 + sr[c][3] * iv3;
    __builtin_nontemporal_store(o, reinterpret_cast<f4*>(out + off));
  }
  // sum_w output
  {
    f4 o;
    o.x = swi.x * sc0 + sw0 * iv0;
    o.y = swi.y * sc1 + sw1 * iv1;
    o.z = swi.z * sc2 + sw2 * iv2;
    o.w = swi.w * sc3 + sw3 * iv3;
    __builtin_nontemporal_store(
        o, reinterpret_cast<f4*>(out + (size_t)BS_ * CH_ * HW_ + pix));
  }
  // new_max output
  {
    f4 o; o.x = nm0; o.y = nm1; o.z = nm2; o.w = nm3;
    __builtin_nontemporal_store(
        o, reinterpret_cast<f4*>(out + (size_t)BS_ * CH_ * HW_ +
                                 (size_t)BS_ * HW_ + pix));
  }
}

// ---------------------------------------------------------------------------
extern "C" void kernel_launch(void* const* d_in, const int* in_sizes, int n_in,
                              void* d_out, int out_size, void* d_ws, size_t ws_size,
                              hipStream_t stream) {
  const float* data  = (const float*)d_in[0];
  const float* kern  = (const float*)d_in[1];
  const float* sum_r = (const float*)d_in[2];
  const float* sum_w = (const float*)d_in[3];
  const float* max_w = (const float*)d_in[4];
  float* out = (float*)d_out;

  dim3 block(128, 1, 1);
  dim3 grid(1, HH, BS_);   // 512 x 4 = 2048 blocks, one full row each

  const size_t padded_bytes = (size_t)BS_ * CH_ * HH * PW_ * sizeof(float);
  if (ws_size >= padded_bytes) {
    float* dpad = (float*)d_ws;
    const int total = BS_ * CH_ * HH * PW_;
    pad_data_kernel<<<(total + 255) / 256, 256, 0, stream>>>(data, dpad);
    pka_kernel<true><<<grid, block, 0, stream>>>(kern, data, dpad, sum_r,
                                                 sum_w, max_w, out);
  } else {
    pka_kernel<false><<<grid, block, 0, stream>>>(kern, data, nullptr, sum_r,
                                                  sum_w, max_w, out);
  }
}